// Round 5
// baseline (241.002 us; speedup 1.0000x reference)
//
#include <hip/hip_runtime.h>
#include <hip/hip_fp16.h>

namespace {

constexpr int kN = 65536;
constexpr int kK = 16;
constexpr int kD = 32;
constexpr int kPts = 2 * kN;                 // 131072 points (B*N)
constexpr int kThreads = 256;
constexpr int kPtsPerBlk = 32;               // 8 lanes per point
constexpr int kBlocks = kPts / kPtsPerBlk;   // 4096
static_assert(kBlocks * kPtsPerBlk == kPts, "grid must tile points exactly");

__device__ __forceinline__ float relu_(float v) { return fmaxf(v, 0.f); }
__device__ __forceinline__ float lrelu_(float v) { return v >= 0.f ? v : 0.2f * v; }

// pack float4 -> 4 fp16 in a uint2
__device__ __forceinline__ uint2 pack_h4(float a, float b, float c, float d) {
    const __half2 h0 = __floats2half2_rn(a, b);
    const __half2 h1 = __floats2half2_rn(c, d);
    uint2 u;
    u.x = *reinterpret_cast<const unsigned int*>(&h0);
    u.y = *reinterpret_cast<const unsigned int*>(&h1);
    return u;
}

__device__ __forceinline__ float4 unpack_h4(uint2 u) {
    const __half2 h0 = *reinterpret_cast<const __half2*>(&u.x);
    const __half2 h1 = *reinterpret_cast<const __half2*>(&u.y);
    const float2 f0 = __half22float2(h0);
    const float2 f1 = __half22float2(h1);
    return make_float4(f0.x, f0.y, f1.x, f1.y);
}

// unpack uint4 (8 fp16) -> 8 floats
__device__ __forceinline__ void unpack_h8(uint4 u, float* f) {
    const __half2* h = reinterpret_cast<const __half2*>(&u);
#pragma unroll
    for (int i = 0; i < 4; ++i) {
        const float2 t = __half22float2(h[i]);
        f[2 * i] = t.x; f[2 * i + 1] = t.y;
    }
}

// z1 = relu((x @ W2_0)*g2_0 + b2_0) in fp16; also pack idx into uint16 pairs.
__global__ __launch_bounds__(kThreads)
void zprep_kernel(const float* __restrict__ src, const int* __restrict__ idx,
                  const float* __restrict__ W2, const float* __restrict__ g2,
                  const float* __restrict__ b2,
                  uint2* __restrict__ z, unsigned int* __restrict__ idx16)
{
    __shared__ alignas(16) float sW2[kD * kD];
    __shared__ float srow[kPtsPerBlk][kD + 1];
    __shared__ float sg2[kD], sb2[kD];
    const int tid = threadIdx.x;
    for (int i = tid; i < kD * kD; i += kThreads) sW2[i] = W2[i];
    if (tid < kD) { sg2[tid] = g2[tid]; sb2[tid] = b2[tid]; }
    const int s  = tid & 7;
    const int pl = tid >> 3;
    const int point = blockIdx.x * kPtsPerBlk + pl;

    const int2 p = reinterpret_cast<const int2*>(idx)[point * 8 + s];
    idx16[point * 8 + s] = (unsigned int)(p.x & 0xFFFF) | ((unsigned int)p.y << 16);

    float4 v = reinterpret_cast<const float4*>(src)[point * 8 + s];
    srow[pl][s * 4 + 0] = v.x; srow[pl][s * 4 + 1] = v.y;
    srow[pl][s * 4 + 2] = v.z; srow[pl][s * 4 + 3] = v.w;
    __syncthreads();
    float ax = 0, ay = 0, az = 0, aw = 0;
#pragma unroll
    for (int d = 0; d < kD; ++d) {
        const float t = srow[pl][d];
        const float4 w = *reinterpret_cast<const float4*>(&sW2[d * kD + s * 4]);
        ax = fmaf(t, w.x, ax); ay = fmaf(t, w.y, ay);
        az = fmaf(t, w.z, az); aw = fmaf(t, w.w, aw);
    }
    z[point * 8 + s] = pack_h4(
        relu_(fmaf(ax, sg2[s * 4 + 0], sb2[s * 4 + 0])),
        relu_(fmaf(ay, sg2[s * 4 + 1], sb2[s * 4 + 1])),
        relu_(fmaf(az, sg2[s * 4 + 2], sb2[s * 4 + 2])),
        relu_(fmaf(aw, sg2[s * 4 + 3], sb2[s * 4 + 3])));
}

// One fused residual block. MODE: 0=first (sacc:=y, cur:=y, t=lrelu(y))
//                                1=mid   (sacc+=y, t=lrelu(y+prev), cur:=y)
//                                2=mid   (sacc+=y, t=lrelu(y+prev), no cur)
//                                3=last  (out = lrelu(sacc+y))
// LDS = weights only (12.8 KB) -> 8 blocks/CU; all row redistribution via
// __shfl inside each point's 8-lane group. Gather uses 16 B uint4 loads:
// lane s reads slice (s&3) of neighbour 2j+(s>>2); one shfl_xor(4) merge.
template <int MODE>
__global__ __launch_bounds__(kThreads, 8)
void blk_kernel(const uint4* __restrict__ zsrc, const unsigned int* __restrict__ idx16,
                const float* __restrict__ W1, const float* __restrict__ g1,
                const float* __restrict__ b1,
                const float* __restrict__ W2n, const float* __restrict__ g2n,
                const float* __restrict__ b2n,
                const uint2* __restrict__ prev, uint2* __restrict__ cur,
                float* __restrict__ sacc, uint2* __restrict__ znext)
{
    __shared__ alignas(16) float sW1[2 * kD * kD];   // 8 KB
    __shared__ alignas(16) float sW2[kD * kD];       // 4 KB
    __shared__ float sg1[kD], sb1[kD], sg2[kD], sb2[kD];
    const int tid = threadIdx.x;
    for (int i = tid; i < 2 * kD * kD; i += kThreads) sW1[i] = W1[i];
    if (MODE != 3) {
        for (int i = tid; i < kD * kD; i += kThreads) sW2[i] = W2n[i];
    }
    if (tid < kD) {
        sg1[tid] = g1[tid]; sb1[tid] = b1[tid];
        if (MODE != 3) { sg2[tid] = g2n[tid]; sb2[tid] = b2n[tid]; }
    }
    const int s    = tid & 7;
    const int pl   = tid >> 3;
    const int grp  = (tid & 63) & ~7;        // 8-lane group base in wave
    const int q    = s & 3;                  // 16 B slice (channels 8q..8q+8)
    const int hi   = s >> 2;                 // 0: even neighbours/max, 1: odd/mean
    const int c4   = s * 4;
    const int point = blockIdx.x * kPtsPerBlk + pl;
    const int base  = point & ~(kN - 1);     // batch offset (b*N)
    const unsigned int pu = idx16[point * 8 + s];
    __syncthreads();

    // ---- gather: 8 x 16 B loads per lane; lane covers 8 channels of 8 nbrs
    float mx[8], sm[8];
#pragma unroll
    for (int c = 0; c < 8; ++c) { mx[c] = 0.f; sm[c] = 0.f; }  // relu out >= 0
#pragma unroll
    for (int j = 0; j < 8; ++j) {
        const unsigned int sel = __shfl(pu, grp + j, 64);
        const int row = hi ? (int)(sel >> 16) : (int)(sel & 0xFFFFu);
        const uint4 u = zsrc[(base + row) * 4 + q];
        float f[8];
        unpack_h8(u, f);
#pragma unroll
        for (int c = 0; c < 8; ++c) { mx[c] = fmaxf(mx[c], f[c]); sm[c] += f[c]; }
    }
    // merge even/odd-neighbour partials (lane s <-> s^4)
#pragma unroll
    for (int c = 0; c < 8; ++c) {
        mx[c] = fmaxf(mx[c], __shfl_xor(mx[c], 4, 64));
        sm[c] = sm[c] + __shfl_xor(sm[c], 4, 64);
    }
    constexpr float inv = 1.f / kK;
    // cat[8j + c] lives on lane grp+j: j<4 -> max slice j, j>=4 -> mean slice j-4
    float vv[8];
#pragma unroll
    for (int c = 0; c < 8; ++c) vv[c] = hi ? sm[c] * inv : mx[c];

    // ---- conv2: y[c4..c4+4) = (cat @ W1) * g1 + b1, cat broadcast via shfl
    float ax = 0, ay = 0, az = 0, aw = 0;
#pragma unroll
    for (int j = 0; j < 8; ++j) {
#pragma unroll
        for (int c = 0; c < 8; ++c) {
            const float cv = __shfl(vv[c], grp + j, 64);
            const float4 w = *reinterpret_cast<const float4*>(&sW1[(8 * j + c) * kD + c4]);
            ax = fmaf(cv, w.x, ax); ay = fmaf(cv, w.y, ay);
            az = fmaf(cv, w.z, az); aw = fmaf(cv, w.w, aw);
        }
    }
    float4 y;
    y.x = fmaf(ax, sg1[c4 + 0], sb1[c4 + 0]);
    y.y = fmaf(ay, sg1[c4 + 1], sb1[c4 + 1]);
    y.z = fmaf(az, sg1[c4 + 2], sb1[c4 + 2]);
    y.w = fmaf(aw, sg1[c4 + 3], sb1[c4 + 3]);

    const int rb = point * 8 + s;
    float4 t;
    if (MODE == 0) {
        reinterpret_cast<float4*>(sacc)[rb] = y;
        cur[rb] = pack_h4(y.x, y.y, y.z, y.w);
        t.x = lrelu_(y.x); t.y = lrelu_(y.y); t.z = lrelu_(y.z); t.w = lrelu_(y.w);
    } else if (MODE == 1 || MODE == 2) {
        float4 sa = reinterpret_cast<const float4*>(sacc)[rb];
        sa.x += y.x; sa.y += y.y; sa.z += y.z; sa.w += y.w;
        reinterpret_cast<float4*>(sacc)[rb] = sa;
        const float4 pv = unpack_h4(prev[rb]);
        t.x = lrelu_(y.x + pv.x); t.y = lrelu_(y.y + pv.y);
        t.z = lrelu_(y.z + pv.z); t.w = lrelu_(y.w + pv.w);
        if (MODE == 1) cur[rb] = pack_h4(y.x, y.y, y.z, y.w);
    } else {  // MODE == 3: final output
        const float4 sa = reinterpret_cast<const float4*>(sacc)[rb];
        float4 o;
        o.x = lrelu_(sa.x + y.x); o.y = lrelu_(sa.y + y.y);
        o.z = lrelu_(sa.z + y.z); o.w = lrelu_(sa.w + y.w);
        reinterpret_cast<float4*>(sacc)[rb] = o;
        return;
    }

    // ---- next layer's z row: z = relu((t @ W2n)*g2n + b2n), t broadcast via shfl
    float zx = 0, zy = 0, zz = 0, zw = 0;
#pragma unroll
    for (int j = 0; j < 8; ++j) {
        const float t0 = __shfl(t.x, grp + j, 64);
        const float t1 = __shfl(t.y, grp + j, 64);
        const float t2 = __shfl(t.z, grp + j, 64);
        const float t3 = __shfl(t.w, grp + j, 64);
        const float4 w0 = *reinterpret_cast<const float4*>(&sW2[(4 * j + 0) * kD + c4]);
        const float4 w1 = *reinterpret_cast<const float4*>(&sW2[(4 * j + 1) * kD + c4]);
        const float4 w2 = *reinterpret_cast<const float4*>(&sW2[(4 * j + 2) * kD + c4]);
        const float4 w3 = *reinterpret_cast<const float4*>(&sW2[(4 * j + 3) * kD + c4]);
        zx = fmaf(t0, w0.x, zx); zy = fmaf(t0, w0.y, zy);
        zz = fmaf(t0, w0.z, zz); zw = fmaf(t0, w0.w, zw);
        zx = fmaf(t1, w1.x, zx); zy = fmaf(t1, w1.y, zy);
        zz = fmaf(t1, w1.z, zz); zw = fmaf(t1, w1.w, zw);
        zx = fmaf(t2, w2.x, zx); zy = fmaf(t2, w2.y, zy);
        zz = fmaf(t2, w2.z, zz); zw = fmaf(t2, w2.w, zw);
        zx = fmaf(t3, w3.x, zx); zy = fmaf(t3, w3.y, zy);
        zz = fmaf(t3, w3.z, zz); zw = fmaf(t3, w3.w, zw);
    }
    znext[rb] = pack_h4(
        relu_(fmaf(zx, sg2[c4 + 0], sb2[c4 + 0])),
        relu_(fmaf(zy, sg2[c4 + 1], sb2[c4 + 1])),
        relu_(fmaf(zz, sg2[c4 + 2], sb2[c4 + 2])),
        relu_(fmaf(zw, sg2[c4 + 3], sb2[c4 + 3])));
}

}  // namespace

extern "C" void kernel_launch(void* const* d_in, const int* in_sizes, int n_in,
                              void* d_out, int out_size, void* d_ws, size_t ws_size,
                              hipStream_t stream)
{
    const float* x   = (const float*)d_in[0];
    const int*   idx = (const int*)d_in[1];
    const float* W2d = (const float*)d_in[2];
    const float* g2  = (const float*)d_in[3];
    const float* b2  = (const float*)d_in[4];
    const float* W1d = (const float*)d_in[5];
    const float* g1  = (const float*)d_in[6];
    const float* b1  = (const float*)d_in[7];
    float* out = (float*)d_out;     // doubles as sacc between dispatches
    char*  ws  = (char*)d_ws;

    constexpr size_t kHalfMap = (size_t)kPts * kD * sizeof(__half);  // 8 MB
    uint2* zA = (uint2*)(ws);
    uint2* zB = (uint2*)(ws + kHalfMap);
    uint2* cA = (uint2*)(ws + 2 * kHalfMap);   // x1 (fp16)
    uint2* cB = (uint2*)(ws + 3 * kHalfMap);   // x2 (fp16)
    unsigned int* idx16 = (unsigned int*)(ws + 4 * kHalfMap);  // 4 MB

    const dim3 grid(kBlocks), blk(kThreads);
    zprep_kernel<<<grid, blk, 0, stream>>>(x, idx, W2d, g2, b2, zA, idx16);
    blk_kernel<0><<<grid, blk, 0, stream>>>((const uint4*)zA, idx16, W1d, g1, b1,
        W2d + 1 * kD * kD, g2 + 1 * kD, b2 + 1 * kD, nullptr, cA, out, zB);
    blk_kernel<1><<<grid, blk, 0, stream>>>((const uint4*)zB, idx16,
        W1d + 1 * 2 * kD * kD, g1 + 1 * kD, b1 + 1 * kD,
        W2d + 2 * kD * kD, g2 + 2 * kD, b2 + 2 * kD, cA, cB, out, zA);
    blk_kernel<2><<<grid, blk, 0, stream>>>((const uint4*)zA, idx16,
        W1d + 2 * 2 * kD * kD, g1 + 2 * kD, b1 + 2 * kD,
        W2d + 3 * kD * kD, g2 + 3 * kD, b2 + 3 * kD, cB, nullptr, out, zB);
    blk_kernel<3><<<grid, blk, 0, stream>>>((const uint4*)zB, idx16,
        W1d + 3 * 2 * kD * kD, g1 + 3 * kD, b1 + 3 * kD,
        nullptr, nullptr, nullptr, nullptr, nullptr, out, nullptr);
}

// Round 6
// 190.140 us; speedup vs baseline: 1.2675x; 1.2675x over previous
//
#include <hip/hip_runtime.h>
#include <hip/hip_fp16.h>

namespace {

typedef _Float16 half8 __attribute__((ext_vector_type(8)));
typedef float f32x4 __attribute__((ext_vector_type(4)));

constexpr int kN = 65536;
constexpr int kD = 32;
constexpr int kPts = 2 * kN;                 // 131072 points (B*N)
constexpr int kThreads = 256;                // 4 waves
constexpr int kPtsPerWave = 16;              // one MFMA M-tile per wave
constexpr int kPtsPerBlk = 64;               // 4 waves * 16 points
constexpr int kBlocks = kPts / kPtsPerBlk;   // 2048
static_assert(kBlocks * kPtsPerBlk == kPts, "grid must tile points exactly");
static_assert(kN % kPtsPerBlk == 0, "blocks must not straddle batch boundary");

__device__ __forceinline__ float relu_(float v) { return fmaxf(v, 0.f); }
__device__ __forceinline__ float lrelu_(float v) { return v >= 0.f ? v : 0.2f * v; }

// B-fragment for mfma_f32_16x16x32_f16: lane holds B[k = q*8+j][n = lane&15].
// W is row-major [K][32] fp32 in global (L2-hot, 4-16 KB); cast to fp16.
__device__ __forceinline__ half8 load_bfrag(const float* __restrict__ W,
                                            int krow0, int ncol, int q)
{
    half8 b;
#pragma unroll
    for (int j = 0; j < 8; ++j)
        b[j] = (_Float16)W[(krow0 + q * 8 + j) * kD + ncol];
    return b;
}

// zprep: z1 = relu((x @ W2_0) * g2_0 + b2_0), fp16 out. Pure MFMA, no LDS.
__global__ __launch_bounds__(kThreads, 4)
void zprep_kernel(const float* __restrict__ x, const float* __restrict__ W2,
                  const float* __restrict__ g2v, const float* __restrict__ b2v,
                  __half* __restrict__ z)
{
    const int tid  = threadIdx.x;
    const int w    = tid >> 6;
    const int lane = tid & 63;
    const int n    = lane & 15;     // output channel (low) / A row
    const int q    = lane >> 4;     // K-quarter
    const int pbase = blockIdx.x * kPtsPerBlk + w * kPtsPerWave;
    const int point = pbase + n;    // A row m = lane&15

    // A-frag: A[m=point][k=q*8+j] = x[point][q*8+j]
    const float4 x0 = reinterpret_cast<const float4*>(x)[point * 8 + q * 2];
    const float4 x1 = reinterpret_cast<const float4*>(x)[point * 8 + q * 2 + 1];
    half8 ax;
    ax[0] = (_Float16)x0.x; ax[1] = (_Float16)x0.y;
    ax[2] = (_Float16)x0.z; ax[3] = (_Float16)x0.w;
    ax[4] = (_Float16)x1.x; ax[5] = (_Float16)x1.y;
    ax[6] = (_Float16)x1.z; ax[7] = (_Float16)x1.w;

    const half8 b0 = load_bfrag(W2, 0, n, q);
    const half8 b1 = load_bfrag(W2, 0, 16 + n, q);
    f32x4 acc0 = {0.f, 0.f, 0.f, 0.f}, acc1 = {0.f, 0.f, 0.f, 0.f};
    acc0 = __builtin_amdgcn_mfma_f32_16x16x32_f16(ax, b0, acc0, 0, 0, 0);
    acc1 = __builtin_amdgcn_mfma_f32_16x16x32_f16(ax, b1, acc1, 0, 0, 0);

    const float g20 = g2v[n], g21 = g2v[16 + n];
    const float c20 = b2v[n], c21 = b2v[16 + n];
    // C/D layout: n = lane&15, m = q*4 + r
#pragma unroll
    for (int r = 0; r < 4; ++r) {
        const int pm = pbase + q * 4 + r;
        z[pm * kD + n]      = __float2half(relu_(fmaf(acc0[r], g20, c20)));
        z[pm * kD + 16 + n] = __float2half(relu_(fmaf(acc1[r], g21, c21)));
    }
}

// One fused residual block. MODE: 0=first (sacc:=y, cur:=y, t=lrelu(y))
//                                1=mid   (sacc+=y, t=lrelu(y+prev), cur:=y)
//                                2=mid   (sacc+=y, t=lrelu(y+prev), no cur)
//                                3=last  (out = lrelu(sacc+y), no z-next)
// Wave = 16 points. Gather reduction lands directly in MFMA A-frag layout.
template <int MODE>
__global__ __launch_bounds__(kThreads, 4)
void blk_kernel(const uint4* __restrict__ zsrc, const int4* __restrict__ idx,
                const float* __restrict__ W1, const float* __restrict__ g1v,
                const float* __restrict__ b1v,
                const float* __restrict__ W2n, const float* __restrict__ g2v,
                const float* __restrict__ b2v,
                const __half* __restrict__ prev, __half* __restrict__ cur,
                float* __restrict__ sacc, __half* __restrict__ znext)
{
    __shared__ __align__(16) _Float16 tb[4][16][40];   // C->A transpose, 5 KB

    const int tid  = threadIdx.x;
    const int w    = tid >> 6;
    const int lane = tid & 63;
    const int n    = lane & 15;
    const int q    = lane >> 4;
    const int pbase = blockIdx.x * kPtsPerBlk + w * kPtsPerWave;
    const int point = pbase + n;            // gather ownership = A row
    const int base  = point & ~(kN - 1);    // batch offset (b*N)

    // 16 neighbour indices for this lane's point
    const int4 i0 = idx[point * 4 + 0];
    const int4 i1 = idx[point * 4 + 1];
    const int4 i2 = idx[point * 4 + 2];
    const int4 i3 = idx[point * 4 + 3];

    // W1 B-frags (K=64 -> chunks A=[0,32) max-part, B=[32,64) mean-part)
    const half8 bA0 = load_bfrag(W1, 0, n, q);
    const half8 bA1 = load_bfrag(W1, 0, 16 + n, q);
    const half8 bB0 = load_bfrag(W1, 32, n, q);
    const half8 bB1 = load_bfrag(W1, 32, 16 + n, q);

    int rows[16];
    rows[0] = i0.x; rows[1] = i0.y; rows[2]  = i0.z; rows[3]  = i0.w;
    rows[4] = i1.x; rows[5] = i1.y; rows[6]  = i1.z; rows[7]  = i1.w;
    rows[8] = i2.x; rows[9] = i2.y; rows[10] = i2.z; rows[11] = i2.w;
    rows[12] = i3.x; rows[13] = i3.y; rows[14] = i3.z; rows[15] = i3.w;

    // gather + online max/sum; lane owns channels q*8..q*8+7 of its point
    float mx[8], sm[8];
#pragma unroll
    for (int c = 0; c < 8; ++c) { mx[c] = 0.f; sm[c] = 0.f; }  // relu out >= 0
#pragma unroll
    for (int k = 0; k < 16; ++k) {
        const uint4 u = zsrc[(base + rows[k]) * 4 + q];
        const __half2* h = reinterpret_cast<const __half2*>(&u);
#pragma unroll
        for (int c = 0; c < 4; ++c) {
            const float2 f = __half22float2(h[c]);
            mx[2 * c]     = fmaxf(mx[2 * c], f.x);     sm[2 * c]     += f.x;
            mx[2 * c + 1] = fmaxf(mx[2 * c + 1], f.y); sm[2 * c + 1] += f.y;
        }
    }
    // A-frags: cat = [max | mean]; reduction output IS the fragment layout
    half8 amax, amean;
#pragma unroll
    for (int c = 0; c < 8; ++c) {
        amax[c]  = (_Float16)mx[c];
        amean[c] = (_Float16)(sm[c] * 0.0625f);
    }

    f32x4 acc0 = {0.f, 0.f, 0.f, 0.f}, acc1 = {0.f, 0.f, 0.f, 0.f};
    acc0 = __builtin_amdgcn_mfma_f32_16x16x32_f16(amax,  bA0, acc0, 0, 0, 0);
    acc0 = __builtin_amdgcn_mfma_f32_16x16x32_f16(amean, bB0, acc0, 0, 0, 0);
    acc1 = __builtin_amdgcn_mfma_f32_16x16x32_f16(amax,  bA1, acc1, 0, 0, 0);
    acc1 = __builtin_amdgcn_mfma_f32_16x16x32_f16(amean, bB1, acc1, 0, 0, 0);

    const float g10 = g1v[n], g11 = g1v[16 + n];
    const float c10 = b1v[n], c11 = b1v[16 + n];

    float t0[4], t1[4];
#pragma unroll
    for (int r = 0; r < 4; ++r) {
        const int pm = pbase + q * 4 + r;            // C/D row m = q*4 + r
        const int o0 = pm * kD + n;
        const int o1 = o0 + 16;
        const float y0 = fmaf(acc0[r], g10, c10);
        const float y1 = fmaf(acc1[r], g11, c11);
        if (MODE == 0) {
            sacc[o0] = y0; sacc[o1] = y1;
            cur[o0] = __float2half(y0); cur[o1] = __float2half(y1);
            t0[r] = lrelu_(y0); t1[r] = lrelu_(y1);
        } else if (MODE == 1 || MODE == 2) {
            sacc[o0] += y0; sacc[o1] += y1;
            const float pv0 = __half2float(prev[o0]);
            const float pv1 = __half2float(prev[o1]);
            t0[r] = lrelu_(y0 + pv0); t1[r] = lrelu_(y1 + pv1);
            if (MODE == 1) { cur[o0] = __float2half(y0); cur[o1] = __float2half(y1); }
        } else {  // MODE == 3: final output
            sacc[o0] = lrelu_(sacc[o0] + y0);
            sacc[o1] = lrelu_(sacc[o1] + y1);
        }
    }
    if (MODE == 3) return;

    // C-layout -> A-layout transpose of t through LDS (per-wave slice)
#pragma unroll
    for (int r = 0; r < 4; ++r) {
        tb[w][q * 4 + r][n]      = (_Float16)t0[r];
        tb[w][q * 4 + r][16 + n] = (_Float16)t1[r];
    }
    __syncthreads();
    const half8 at = *reinterpret_cast<const half8*>(&tb[w][n][q * 8]);

    // next layer's z: Z = relu((T @ W2n) * g2n + b2n), K=32 -> 1 MFMA per n-tile
    const half8 bz0 = load_bfrag(W2n, 0, n, q);
    const half8 bz1 = load_bfrag(W2n, 0, 16 + n, q);
    f32x4 az0 = {0.f, 0.f, 0.f, 0.f}, az1 = {0.f, 0.f, 0.f, 0.f};
    az0 = __builtin_amdgcn_mfma_f32_16x16x32_f16(at, bz0, az0, 0, 0, 0);
    az1 = __builtin_amdgcn_mfma_f32_16x16x32_f16(at, bz1, az1, 0, 0, 0);

    const float g20 = g2v[n], g21 = g2v[16 + n];
    const float c20 = b2v[n], c21 = b2v[16 + n];
#pragma unroll
    for (int r = 0; r < 4; ++r) {
        const int pm = pbase + q * 4 + r;
        znext[pm * kD + n]      = __float2half(relu_(fmaf(az0[r], g20, c20)));
        znext[pm * kD + 16 + n] = __float2half(relu_(fmaf(az1[r], g21, c21)));
    }
}

}  // namespace

extern "C" void kernel_launch(void* const* d_in, const int* in_sizes, int n_in,
                              void* d_out, int out_size, void* d_ws, size_t ws_size,
                              hipStream_t stream)
{
    const float* x   = (const float*)d_in[0];
    const int4*  idx = (const int4*)d_in[1];
    const float* W2d = (const float*)d_in[2];
    const float* g2  = (const float*)d_in[3];
    const float* b2  = (const float*)d_in[4];
    const float* W1d = (const float*)d_in[5];
    const float* g1  = (const float*)d_in[6];
    const float* b1  = (const float*)d_in[7];
    float* out = (float*)d_out;     // doubles as sacc between dispatches
    char*  ws  = (char*)d_ws;

    constexpr size_t kHalfMap = (size_t)kPts * kD * sizeof(__half);  // 8 MB
    __half* zA = (__half*)(ws);
    __half* zB = (__half*)(ws + kHalfMap);
    __half* cA = (__half*)(ws + 2 * kHalfMap);   // x1 (fp16)
    __half* cB = (__half*)(ws + 3 * kHalfMap);   // x2 (fp16)

    const dim3 grid(kBlocks), blk(kThreads);
    zprep_kernel<<<grid, blk, 0, stream>>>(x, W2d, g2, b2, zA);
    blk_kernel<0><<<grid, blk, 0, stream>>>((const uint4*)zA, idx, W1d, g1, b1,
        W2d + 1 * kD * kD, g2 + 1 * kD, b2 + 1 * kD, nullptr, cA, out, zB);
    blk_kernel<1><<<grid, blk, 0, stream>>>((const uint4*)zB, idx,
        W1d + 1 * 2 * kD * kD, g1 + 1 * kD, b1 + 1 * kD,
        W2d + 2 * kD * kD, g2 + 2 * kD, b2 + 2 * kD, cA, cB, out, zA);
    blk_kernel<2><<<grid, blk, 0, stream>>>((const uint4*)zA, idx,
        W1d + 2 * 2 * kD * kD, g1 + 2 * kD, b1 + 2 * kD,
        W2d + 3 * kD * kD, g2 + 3 * kD, b2 + 3 * kD, cB, nullptr, out, zB);
    blk_kernel<3><<<grid, blk, 0, stream>>>((const uint4*)zB, idx,
        W1d + 3 * 2 * kD * kD, g1 + 3 * kD, b1 + 3 * kD,
        nullptr, nullptr, nullptr, nullptr, nullptr, out, nullptr);
}

// Round 7
// 186.694 us; speedup vs baseline: 1.2909x; 1.0185x over previous
//
#include <hip/hip_runtime.h>
#include <hip/hip_fp16.h>

namespace {

typedef _Float16 half8 __attribute__((ext_vector_type(8)));
typedef float f32x4 __attribute__((ext_vector_type(4)));

constexpr int kN = 65536;
constexpr int kD = 32;
constexpr int kPts = 2 * kN;                 // 131072 points (B*N)
constexpr int kThreads = 256;                // 4 waves
constexpr int kPtsPerBlk = 64;               // 16 points per wave
constexpr int kBlocks = kPts / kPtsPerBlk;   // 2048
constexpr int kNumFrags = 24;                // 2 zprep + 3*6 + 4
static_assert(kBlocks * kPtsPerBlk == kPts, "grid must tile points exactly");
static_assert(kN % kPtsPerBlk == 0, "blocks must not straddle batch boundary");

__device__ __forceinline__ float relu_(float v) { return fmaxf(v, 0.f); }
__device__ __forceinline__ float lrelu_(float v) { return v >= 0.f ? v : 0.2f * v; }

// channel permutation induced by the interleaved z-row layout:
// row = 16 half2 slots, slot n holds (ch n, ch n+16).
// A/B fragment index k -> real channel pi(k).
__device__ __forceinline__ int pi_(int k) {
    const int c = ((k >> 3) << 2) + ((k & 7) >> 1);
    return (k & 1) ? c + 16 : c;
}

// ---------------------------------------------------------------------------
// pack_kernel: one small block converts all weights to fp16 B-fragments,
// laid out [frag][lane] so a lane's whole fragment is ONE dwordx4 load.
// frag 0,1:       zprep W2_0, natural rows, h = frag (output-col half)
// frag 2+6i+s:    blk layer i (i=0..3; layer 3 has only 4 frags):
//                 s=0..3: W1, rows p*32 + pi(k), p=s>>1, h=s&1
//                 s=4,5:  W2_{i+1}, rows pi(k), h=s-4
// ---------------------------------------------------------------------------
__global__ __launch_bounds__(kThreads)
void pack_kernel(const float* __restrict__ W2d, const float* __restrict__ W1d,
                 uint4* __restrict__ wpack)
{
    for (int id = threadIdx.x; id < kNumFrags * 64; id += kThreads) {
        const int fid = id >> 6, l = id & 63, n = l & 15, q = l >> 4;
        half8 v;
        if (fid < 2) {
            const int h = fid;
#pragma unroll
            for (int j = 0; j < 8; ++j)
                v[j] = (_Float16)W2d[(q * 8 + j) * kD + h * 16 + n];
        } else {
            const int rel = fid - 2;
            const int layer = (rel < 18) ? rel / 6 : 3;
            const int sub   = (rel < 18) ? rel % 6 : rel - 18;
            if (sub < 4) {
                const int p = sub >> 1, h = sub & 1;
#pragma unroll
                for (int j = 0; j < 8; ++j)
                    v[j] = (_Float16)W1d[layer * 2048 + (p * 32 + pi_(q * 8 + j)) * kD + h * 16 + n];
            } else {
                const int h = sub - 4;
#pragma unroll
                for (int j = 0; j < 8; ++j)
                    v[j] = (_Float16)W2d[(layer + 1) * 1024 + pi_(q * 8 + j) * kD + h * 16 + n];
            }
        }
        wpack[id] = *reinterpret_cast<const uint4*>(&v);
    }
}

// ---------------------------------------------------------------------------
// zprep: z1 = relu((x @ W2_0) * g2_0 + b2_0), stored interleaved fp16;
// also packs idx (int32) -> idx16 (u16), 32 B per point.
// ---------------------------------------------------------------------------
__global__ __launch_bounds__(kThreads, 4)
void zprep_kernel(const float* __restrict__ x, const int4* __restrict__ idx4,
                  const uint4* __restrict__ wfrag,
                  const float* __restrict__ g2v, const float* __restrict__ b2v,
                  __half2* __restrict__ z, uint2* __restrict__ idx16)
{
    const int tid  = threadIdx.x;
    // --- idx pack: thread handles 4 indices (8 B out), fully coalesced ---
    {
        const int p = blockIdx.x * kPtsPerBlk + (tid >> 2);
        const int part = tid & 3;
        const int4 iv = idx4[p * 4 + part];
        uint2 o;
        o.x = (unsigned)(iv.x & 0xFFFF) | ((unsigned)iv.y << 16);
        o.y = (unsigned)(iv.z & 0xFFFF) | ((unsigned)iv.w << 16);
        idx16[p * 4 + part] = o;
    }
    // --- z1 via MFMA ---
    const int w    = tid >> 6;
    const int lane = tid & 63;
    const int n    = lane & 15;
    const int q    = lane >> 4;
    const int pbase = blockIdx.x * kPtsPerBlk + w * 16;
    const int point = pbase + n;

    const float4 x0 = reinterpret_cast<const float4*>(x)[point * 8 + q * 2];
    const float4 x1 = reinterpret_cast<const float4*>(x)[point * 8 + q * 2 + 1];
    half8 ax;
    ax[0] = (_Float16)x0.x; ax[1] = (_Float16)x0.y;
    ax[2] = (_Float16)x0.z; ax[3] = (_Float16)x0.w;
    ax[4] = (_Float16)x1.x; ax[5] = (_Float16)x1.y;
    ax[6] = (_Float16)x1.z; ax[7] = (_Float16)x1.w;

    const uint4 u0 = wfrag[0 * 64 + lane];
    const uint4 u1 = wfrag[1 * 64 + lane];
    const half8 b0 = *reinterpret_cast<const half8*>(&u0);
    const half8 b1 = *reinterpret_cast<const half8*>(&u1);
    f32x4 a0 = {0.f, 0.f, 0.f, 0.f}, a1 = {0.f, 0.f, 0.f, 0.f};
    a0 = __builtin_amdgcn_mfma_f32_16x16x32_f16(ax, b0, a0, 0, 0, 0);
    a1 = __builtin_amdgcn_mfma_f32_16x16x32_f16(ax, b1, a1, 0, 0, 0);

    const float g20 = g2v[n], g21 = g2v[16 + n];
    const float c20 = b2v[n], c21 = b2v[16 + n];
#pragma unroll
    for (int r = 0; r < 4; ++r) {
        const int pm = pbase + q * 4 + r;      // C/D row m = q*4 + r
        z[pm * 16 + n] = __floats2half2_rn(relu_(fmaf(a0[r], g20, c20)),
                                           relu_(fmaf(a1[r], g21, c21)));
    }
}

// ---------------------------------------------------------------------------
// blk: gather (interleaved z) -> max/mean (lands in A-frag layout) ->
// MFMA conv2 -> fp32 LDS transpose (wave-local, NO block barrier) ->
// A-layout vectorized epilogue -> MFMA z-next -> C-layout-native z store.
// MODE: 0=first, 1=mid(+cur), 2=mid, 3=last.
// ---------------------------------------------------------------------------
template <int MODE>
__global__ __launch_bounds__(kThreads, 4)
void blk_kernel(const uint4* __restrict__ zsrc, const uint4* __restrict__ idx16,
                const uint4* __restrict__ wfrag,
                const float* __restrict__ g1v, const float* __restrict__ b1v,
                const float* __restrict__ g2v, const float* __restrict__ b2v,
                const uint4* __restrict__ prev, uint4* __restrict__ cur,
                float* __restrict__ sacc, __half2* __restrict__ znext)
{
    __shared__ float2 tb[4][16][17];   // [wave][point][slot], stride 17 -> 2-way max

    const int tid  = threadIdx.x;
    const int w    = tid >> 6;
    const int lane = tid & 63;
    const int n    = lane & 15;
    const int q    = lane >> 4;
    const int pbase = blockIdx.x * kPtsPerBlk + w * 16;
    const int point = pbase + n;
    const int base  = pbase & ~(kN - 1);       // batch offset (wave-uniform)

    // 16 packed neighbour ids (u16) for this lane's point: 2 coalesced dwordx4
    const uint4 iv0 = idx16[point * 2 + 0];
    const uint4 iv1 = idx16[point * 2 + 1];

    // weight fragments: one dwordx4 each
    const uint4 f0 = wfrag[0 * 64 + lane];
    const uint4 f1 = wfrag[1 * 64 + lane];
    const uint4 f2 = wfrag[2 * 64 + lane];
    const uint4 f3 = wfrag[3 * 64 + lane];
    const half8 bA0 = *reinterpret_cast<const half8*>(&f0);  // W1 max, cols 0-15
    const half8 bA1 = *reinterpret_cast<const half8*>(&f1);  // W1 max, cols 16-31
    const half8 bB0 = *reinterpret_cast<const half8*>(&f2);  // W1 mean, cols 0-15
    const half8 bB1 = *reinterpret_cast<const half8*>(&f3);  // W1 mean, cols 16-31

    // ---- gather + online max/sum; lane owns slice q of its point ----
    float mx[8], sm[8];
#pragma unroll
    for (int c = 0; c < 8; ++c) { mx[c] = 0.f; sm[c] = 0.f; }   // relu out >= 0
    const unsigned* ivw = reinterpret_cast<const unsigned*>(&iv0);  // iv0,iv1 contiguous? no
#pragma unroll
    for (int k = 0; k < 16; ++k) {
        unsigned word;
        if (k < 8) word = reinterpret_cast<const unsigned*>(&iv0)[k >> 1];
        else       word = reinterpret_cast<const unsigned*>(&iv1)[(k - 8) >> 1];
        const int row = (k & 1) ? (int)(word >> 16) : (int)(word & 0xFFFFu);
        const uint4 u = zsrc[(base + row) * 4 + q];
        const __half2* h = reinterpret_cast<const __half2*>(&u);
#pragma unroll
        for (int c = 0; c < 4; ++c) {
            const float2 f = __half22float2(h[c]);
            mx[2 * c]     = fmaxf(mx[2 * c], f.x);     sm[2 * c]     += f.x;
            mx[2 * c + 1] = fmaxf(mx[2 * c + 1], f.y); sm[2 * c + 1] += f.y;
        }
    }
    (void)ivw;
    half8 amax, amean;
#pragma unroll
    for (int c = 0; c < 8; ++c) {
        amax[c]  = (_Float16)mx[c];
        amean[c] = (_Float16)(sm[c] * 0.0625f);
    }

    // ---- conv2 MFMA ----
    f32x4 acc0 = {0.f, 0.f, 0.f, 0.f}, acc1 = {0.f, 0.f, 0.f, 0.f};
    acc0 = __builtin_amdgcn_mfma_f32_16x16x32_f16(amax,  bA0, acc0, 0, 0, 0);
    acc0 = __builtin_amdgcn_mfma_f32_16x16x32_f16(amean, bB0, acc0, 0, 0, 0);
    acc1 = __builtin_amdgcn_mfma_f32_16x16x32_f16(amax,  bA1, acc1, 0, 0, 0);
    acc1 = __builtin_amdgcn_mfma_f32_16x16x32_f16(amean, bB1, acc1, 0, 0, 0);

    // BN fold in C-layout (lane holds channels n and n+16)
    const float g10 = g1v[n], g11 = g1v[16 + n];
    const float c10 = b1v[n], c11 = b1v[16 + n];
    // C->A transpose through wave-local LDS (no block barrier needed:
    // writers and readers of tb[w] are the same wave; DS is wave-ordered)
#pragma unroll
    for (int r = 0; r < 4; ++r) {
        tb[w][q * 4 + r][n] = make_float2(fmaf(acc0[r], g10, c10),
                                          fmaf(acc1[r], g11, c11));
    }
    __builtin_amdgcn_wave_barrier();
    float y8[8];
#pragma unroll
    for (int s = 0; s < 4; ++s) {
        const float2 f = tb[w][n][q * 4 + s];
        y8[2 * s] = f.x; y8[2 * s + 1] = f.y;
    }

    // ---- A-layout epilogue: vectorized global I/O ----
    const int sb0 = point * kD + q * 4;        // natural-order channels q*4..+4
    const int sb1 = sb0 + 16;                  // channels 16+q*4..+4
    float t8[8];
    if (MODE == 0) {
        reinterpret_cast<float4*>(sacc)[sb0 >> 2] = make_float4(y8[0], y8[2], y8[4], y8[6]);
        reinterpret_cast<float4*>(sacc)[sb1 >> 2] = make_float4(y8[1], y8[3], y8[5], y8[7]);
        half8 ch;
#pragma unroll
        for (int c = 0; c < 8; ++c) ch[c] = (_Float16)y8[c];
        cur[point * 4 + q] = *reinterpret_cast<const uint4*>(&ch);
#pragma unroll
        for (int c = 0; c < 8; ++c) t8[c] = lrelu_(y8[c]);
    } else if (MODE == 1 || MODE == 2) {
        float4 s0 = reinterpret_cast<const float4*>(sacc)[sb0 >> 2];
        float4 s1 = reinterpret_cast<const float4*>(sacc)[sb1 >> 2];
        s0.x += y8[0]; s0.y += y8[2]; s0.z += y8[4]; s0.w += y8[6];
        s1.x += y8[1]; s1.y += y8[3]; s1.z += y8[5]; s1.w += y8[7];
        reinterpret_cast<float4*>(sacc)[sb0 >> 2] = s0;
        reinterpret_cast<float4*>(sacc)[sb1 >> 2] = s1;
        const uint4 pv = prev[point * 4 + q];
        const __half2* ph = reinterpret_cast<const __half2*>(&pv);
#pragma unroll
        for (int c = 0; c < 4; ++c) {
            const float2 f = __half22float2(ph[c]);
            t8[2 * c]     = lrelu_(y8[2 * c] + f.x);
            t8[2 * c + 1] = lrelu_(y8[2 * c + 1] + f.y);
        }
        if (MODE == 1) {
            half8 ch;
#pragma unroll
            for (int c = 0; c < 8; ++c) ch[c] = (_Float16)y8[c];
            cur[point * 4 + q] = *reinterpret_cast<const uint4*>(&ch);
        }
    } else {  // MODE == 3: out = lrelu(sacc + y), natural order
        const float4 s0 = reinterpret_cast<const float4*>(sacc)[sb0 >> 2];
        const float4 s1 = reinterpret_cast<const float4*>(sacc)[sb1 >> 2];
        reinterpret_cast<float4*>(sacc)[sb0 >> 2] =
            make_float4(lrelu_(s0.x + y8[0]), lrelu_(s0.y + y8[2]),
                        lrelu_(s0.z + y8[4]), lrelu_(s0.w + y8[6]));
        reinterpret_cast<float4*>(sacc)[sb1 >> 2] =
            make_float4(lrelu_(s1.x + y8[1]), lrelu_(s1.y + y8[3]),
                        lrelu_(s1.z + y8[5]), lrelu_(s1.w + y8[7]));
        return;
    }

    // ---- z-next: T already in A-frag (pi) order; MFMA; C-layout-native store
    half8 at;
#pragma unroll
    for (int c = 0; c < 8; ++c) at[c] = (_Float16)t8[c];
    const uint4 f4 = wfrag[4 * 64 + lane];
    const uint4 f5 = wfrag[5 * 64 + lane];
    const half8 bz0 = *reinterpret_cast<const half8*>(&f4);
    const half8 bz1 = *reinterpret_cast<const half8*>(&f5);
    f32x4 az0 = {0.f, 0.f, 0.f, 0.f}, az1 = {0.f, 0.f, 0.f, 0.f};
    az0 = __builtin_amdgcn_mfma_f32_16x16x32_f16(at, bz0, az0, 0, 0, 0);
    az1 = __builtin_amdgcn_mfma_f32_16x16x32_f16(at, bz1, az1, 0, 0, 0);

    const float g20 = g2v[n], g21 = g2v[16 + n];
    const float c20 = b2v[n], c21 = b2v[16 + n];
#pragma unroll
    for (int r = 0; r < 4; ++r) {
        const int pm = pbase + q * 4 + r;
        znext[pm * 16 + n] = __floats2half2_rn(relu_(fmaf(az0[r], g20, c20)),
                                               relu_(fmaf(az1[r], g21, c21)));
    }
}

}  // namespace

extern "C" void kernel_launch(void* const* d_in, const int* in_sizes, int n_in,
                              void* d_out, int out_size, void* d_ws, size_t ws_size,
                              hipStream_t stream)
{
    const float* x   = (const float*)d_in[0];
    const int4*  idx = (const int4*)d_in[1];
    const float* W2d = (const float*)d_in[2];
    const float* g2  = (const float*)d_in[3];
    const float* b2  = (const float*)d_in[4];
    const float* W1d = (const float*)d_in[5];
    const float* g1  = (const float*)d_in[6];
    const float* b1  = (const float*)d_in[7];
    float* out = (float*)d_out;     // doubles as sacc between dispatches
    char*  ws  = (char*)d_ws;

    constexpr size_t kHalfMap = (size_t)kPts * kD * sizeof(__half);  // 8 MB
    __half2* zA = (__half2*)(ws);
    __half2* zB = (__half2*)(ws + kHalfMap);
    uint4*   cA = (uint4*)(ws + 2 * kHalfMap);                 // x1 (fp16, pi order)
    uint4*   cB = (uint4*)(ws + 3 * kHalfMap);                 // x2 (fp16, pi order)
    uint2*   idx16 = (uint2*)(ws + 4 * kHalfMap);              // 4 MB
    uint4*   wpack = (uint4*)(ws + 4 * kHalfMap + (size_t)kPts * 32);  // 24 KB

    const dim3 grid(kBlocks), blk(kThreads);
    pack_kernel<<<dim3(1), blk, 0, stream>>>(W2d, W1d, wpack);
    zprep_kernel<<<grid, blk, 0, stream>>>(x, idx, wpack, g2, b2, zA, idx16);

    const uint4* i16 = (const uint4*)idx16;
    blk_kernel<0><<<grid, blk, 0, stream>>>((const uint4*)zA, i16,
        wpack + (2 + 0 * 6) * 64, g1, b1, g2 + 1 * kD, b2 + 1 * kD,
        nullptr, cA, out, zB);
    blk_kernel<1><<<grid, blk, 0, stream>>>((const uint4*)zB, i16,
        wpack + (2 + 1 * 6) * 64, g1 + 1 * kD, b1 + 1 * kD, g2 + 2 * kD, b2 + 2 * kD,
        cA, cB, out, zA);
    blk_kernel<2><<<grid, blk, 0, stream>>>((const uint4*)zA, i16,
        wpack + (2 + 2 * 6) * 64, g1 + 2 * kD, b1 + 2 * kD, g2 + 3 * kD, b2 + 3 * kD,
        cB, nullptr, out, zB);
    blk_kernel<3><<<grid, blk, 0, stream>>>((const uint4*)zB, i16,
        wpack + (2 + 3 * 6) * 64, g1 + 3 * kD, b1 + 3 * kD, nullptr, nullptr,
        nullptr, nullptr, out, nullptr);
}